// Round 10
// baseline (114.705 us; speedup 1.0000x reference)
//
#include <hip/hip_runtime.h>
#include <math.h>

constexpr int B_ = 64, Q_ = 900, N_ = 100, C_ = 256;
constexpr float EPSF = 1e-6f;
constexpr float BOX_W = 5.0f, GIOU_W = 2.0f, CLS_W = 1.0f;
constexpr int KP = 15;   // preds per lane: 64*15 >= 900
constexpr int T_ = 10;   // targets per chunk
constexpr int CH_ = 10;  // chunks
typedef unsigned long long u64;
typedef unsigned int u32;

__device__ __forceinline__ float giou_f(float px0, float py0, float px1, float py1, float pa,
                                        float tx0, float ty0, float tx1, float ty1, float ta) {
    float ltx = fmaxf(px0, tx0), lty = fmaxf(py0, ty0);
    float rbx = fminf(px1, tx1), rby = fminf(py1, ty1);
    float w = fmaxf(rbx - ltx, 0.0f), h = fmaxf(rby - lty, 0.0f);
    float inter = w * h;
    float uni = pa + ta - inter;
    float iou = inter / (uni + EPSF);
    float ex0 = fminf(px0, tx0), ey0 = fminf(py0, ty0);
    float ex1 = fmaxf(px1, tx1), ey1 = fmaxf(py1, ty1);
    float ew = fmaxf(ex1 - ex0, 0.0f), eh = fmaxf(ey1 - ey0, 0.0f);
    float earea = ew * eh;
    return iou - (earea - uni) / (earea + EPSF);
}

// order-preserving float->uint (bijective): a>b as float <=> f2ord(a)>f2ord(b)
__device__ __forceinline__ u32 f2ord(float f) {
    u32 u = __float_as_uint(f);
    return (u & 0x80000000u) ? ~u : (u | 0x80000000u);
}

// canonical GCN wave64 max-reduce via DPP (rocPRIM pattern), result broadcast from lane 63
__device__ __forceinline__ u32 wave_max_u32(u32 x) {
    u32 t;
    t = (u32)__builtin_amdgcn_update_dpp((int)x, (int)x, 0x111, 0xf, 0xf, false); x = x > t ? x : t; // row_shr:1
    t = (u32)__builtin_amdgcn_update_dpp((int)x, (int)x, 0x112, 0xf, 0xf, false); x = x > t ? x : t; // row_shr:2
    t = (u32)__builtin_amdgcn_update_dpp((int)x, (int)x, 0x114, 0xf, 0xe, false); x = x > t ? x : t; // row_shr:4
    t = (u32)__builtin_amdgcn_update_dpp((int)x, (int)x, 0x118, 0xf, 0xc, false); x = x > t ? x : t; // row_shr:8
    t = (u32)__builtin_amdgcn_update_dpp((int)x, (int)x, 0x142, 0xa, 0xf, false); x = x > t ? x : t; // row_bcast:15
    t = (u32)__builtin_amdgcn_update_dpp((int)x, (int)x, 0x143, 0xc, 0xf, false); x = x > t ? x : t; // row_bcast:31
    return (u32)__builtin_amdgcn_readlane((int)x, 63);
}

// compute one target's exact-u32 column into LDS planes [KP][64] (lane stride 4B: conflict-free)
__device__ __forceinline__ void compute_col(
    u32 (*smat)[64], int nl, int n, int lane,
    const float* px0, const float* py0, const float* px1, const float* py1, const float* pa,
    const float* tx0s, const float* ty0s, const float* tx1s, const float* ty1s, const float* tas)
{
    float tx0 = tx0s[n], ty0 = ty0s[n], tx1 = tx1s[n], ty1 = ty1s[n], ta = tas[n];
    #pragma unroll
    for (int k = 0; k < KP; ++k) {
        int q = lane + (k << 6);
        u32 val = 0u;
        if (q < Q_) {
            float g = giou_f(px0[k], py0[k], px1[k], py1[k], pa[k], tx0, ty0, tx1, ty1, ta);
            val = f2ord(g);
        }
        smat[nl * KP + k][lane] = val;
    }
}

__global__ __launch_bounds__(256, 1) void fused_kernel(
    const float* __restrict__ pred_boxes,    // [B,Q,4] cxcywh
    const float* __restrict__ pred_logits,   // [B,Q,C]
    const float* __restrict__ target_boxes,  // [B,N,4] xyxy
    const int*   __restrict__ target_labels, // [B,N]
    double* __restrict__ partial,            // [B]
    u32* __restrict__ cnt,                   // zeroed by async memset each launch
    float* __restrict__ out)
{
    const int b = blockIdx.x;
    const int tid = threadIdx.x;
    const int lane = tid & 63;
    const int wid = tid >> 6;

    __shared__ u32 s_mat[2][T_ * KP][64];    // 76.8 KB exact-ord planes, double-buffered
    __shared__ float tx0s[N_], ty0s[N_], tx1s[N_], ty1s[N_], tas[N_];
    __shared__ int labs[N_], s_ms[N_];
    __shared__ double red[256];
    __shared__ int s_last;

    // ---- P0: targets + labels + per-lane pred boxes (all waves) ----
    if (tid < N_) {
        const float4 t4 = ((const float4*)(target_boxes + (size_t)b * N_ * 4))[tid];
        tx0s[tid] = t4.x; ty0s[tid] = t4.y; tx1s[tid] = t4.z; ty1s[tid] = t4.w;
        tas[tid] = (t4.z - t4.x) * (t4.w - t4.y);
        labs[tid] = target_labels[b * N_ + tid];
    }
    float px0[KP], py0[KP], px1[KP], py1[KP], pa[KP];
    const float4* pbv = (const float4*)(pred_boxes + (size_t)b * Q_ * 4);
    #pragma unroll
    for (int k = 0; k < KP; ++k) {
        int q = lane + (k << 6);
        px0[k] = py0[k] = px1[k] = py1[k] = pa[k] = 0.0f;
        if (q < Q_) {
            float4 c = pbv[q];
            px0[k] = c.x - 0.5f * c.z; py0[k] = c.y - 0.5f * c.w;
            px1[k] = c.x + 0.5f * c.z; py1[k] = c.y + 0.5f * c.w;
            pa[k] = (px1[k] - px0[k]) * (py1[k] - py0[k]);
        }
    }
    __syncthreads();

    // ---- prologue: all 4 waves compute chunk 0 ----
    for (int nl = wid; nl < T_; nl += 4)
        compute_col(s_mat[0], nl, nl, lane, px0, py0, px1, py1, pa,
                    tx0s, ty0s, tx1s, ty1s, tas);
    __syncthreads();

    double acc = 0.0;
    u32 um = 0u;  // used bits among this lane's KP preds (resolve wave only)
    const float* lgbase = pred_logits + (size_t)b * Q_ * C_;

    // ---- pipelined main loop: wave0 resolves c; waves1-3 stage c+1 then BCE c-1 ----
    for (int c = 0; c < CH_; ++c) {
        if (wid == 0) {
            const u32 (*smat)[64] = s_mat[c & 1];
            u32 wcur[KP];
            #pragma unroll
            for (int k = 0; k < KP; ++k) wcur[k] = smat[k][lane];
            #pragma unroll 1
            for (int nl = 0; nl < T_; ++nl) {
                const int n = c * T_ + nl;
                // prefetch next target's column (hides LDS latency under the scan)
                u32 wnext[KP];
                #pragma unroll
                for (int k = 0; k < KP; ++k)
                    wnext[k] = (nl + 1 < T_) ? smat[(nl + 1) * KP + k][lane] : 0u;
                // masked in-lane argmax (first occurrence wins => min k => min q on in-lane ties)
                u32 t1 = 0u; int k1 = 0;
                #pragma unroll
                for (int k = 0; k < KP; ++k) {
                    u32 v = ((um >> k) & 1u) ? 0u : wcur[k];
                    bool gt = v > t1;
                    k1 = gt ? k : k1;
                    t1 = gt ? v : t1;
                }
                // wave max via DPP (VALU-speed), then winner by ballot
                u32 wval = wave_max_u32(t1);
                u64 bal = __ballot(t1 == wval);
                int lt = (int)__builtin_ctzll(bal);
                int wq = lt + (__builtin_amdgcn_readlane(k1, lt) << 6);
                if (__popcll(bal) > 1) {  // exact f32 ties only: pick min q
                    u64 mm = bal & (bal - 1);
                    while (mm) {
                        int l2 = (int)__builtin_ctzll(mm);
                        int qq = l2 + (__builtin_amdgcn_readlane(k1, l2) << 6);
                        wq = qq < wq ? qq : wq;
                        mm &= mm - 1;
                    }
                }
                if (lane == (wq & 63)) um |= 1u << (wq >> 6);
                if (lane == 0) s_ms[n] = wq;
                #pragma unroll
                for (int k = 0; k < KP; ++k) wcur[k] = wnext[k];
            }
        } else {
            if (c + 1 < CH_) {
                for (int nl = wid - 1; nl < T_; nl += 3)
                    compute_col(s_mat[(c + 1) & 1], nl, (c + 1) * T_ + nl, lane,
                                px0, py0, px1, py1, pa, tx0s, ty0s, tx1s, ty1s, tas);
            }
            if (c >= 1) {
                // BCE for chunk c-1 (s_ms visible since last barrier)
                for (int nl = wid - 1; nl < T_; nl += 3) {
                    const int n = (c - 1) * T_ + nl;
                    int q = s_ms[n];
                    int lab = labs[n];
                    const float4 xv = *(const float4*)(lgbase + (size_t)q * C_ + lane * 4);
                    float xs[4] = {xv.x, xv.y, xv.z, xv.w};
                    int base = lane * 4;
                    #pragma unroll
                    for (int j = 0; j < 4; ++j) {
                        float x = xs[j];
                        float tt = (base + j == lab) ? 1.0f : 0.0f;
                        acc += (double)(fmaxf(x, 0.0f) - x * tt + log1pf(expf(-fabsf(x))));
                    }
                }
            }
        }
        __syncthreads();
    }

    // ---- tail BCE: last chunk, all 4 waves ----
    for (int nl = wid; nl < T_; nl += 4) {
        const int n = (CH_ - 1) * T_ + nl;
        int q = s_ms[n];
        int lab = labs[n];
        const float4 xv = *(const float4*)(lgbase + (size_t)q * C_ + lane * 4);
        float xs[4] = {xv.x, xv.y, xv.z, xv.w};
        int base = lane * 4;
        #pragma unroll
        for (int j = 0; j < 4; ++j) {
            float x = xs[j];
            float tt = (base + j == lab) ? 1.0f : 0.0f;
            acc += (double)(fmaxf(x, 0.0f) - x * tt + log1pf(expf(-fabsf(x))));
        }
    }
    acc *= (double)CLS_W;

    // ---- box losses: one target per thread (tid < 100) ----
    if (tid < N_) {
        int q = s_ms[tid];
        float4 c = pbv[q];
        float tx0 = tx0s[tid], ty0 = ty0s[tid], tx1 = tx1s[tid], ty1 = ty1s[tid];
        float tcx = (tx0 + tx1) * 0.5f, tcy = (ty0 + ty1) * 0.5f;
        float tw = tx1 - tx0, th = ty1 - ty0;
        float l1 = fabsf(c.x - tcx) + fabsf(c.y - tcy) + fabsf(c.z - tw) + fabsf(c.w - th);
        float x0 = c.x - 0.5f * c.z, y0 = c.y - 0.5f * c.w;
        float x1 = c.x + 0.5f * c.z, y1 = c.y + 0.5f * c.w;
        float pa2 = (x1 - x0) * (y1 - y0);
        float g = giou_f(x0, y0, x1, y1, pa2, tx0, ty0, tx1, ty1, tas[tid]);
        acc += (double)(BOX_W * l1) + (double)(GIOU_W * (1.0f - g));
    }

    // ---- block reduce (fixed-order tree) ----
    red[tid] = acc;
    __syncthreads();
    #pragma unroll
    for (int s = 128; s >= 1; s >>= 1) {
        if (tid < s) red[tid] += red[tid + s];
        __syncthreads();
    }

    // ---- last-block finalize (cnt zeroed by async memset each launch) ----
    if (tid == 0) {
        __hip_atomic_store(&partial[b], red[0], __ATOMIC_RELEASE, __HIP_MEMORY_SCOPE_AGENT);
        u32 old = __hip_atomic_fetch_add(cnt, 1u, __ATOMIC_ACQ_REL, __HIP_MEMORY_SCOPE_AGENT);
        s_last = (old == (u32)(B_ - 1)) ? 1 : 0;
    }
    __syncthreads();
    if (s_last && tid < 64) {
        double v = __hip_atomic_load(&partial[lane], __ATOMIC_ACQUIRE, __HIP_MEMORY_SCOPE_AGENT);
        #pragma unroll
        for (int off = 32; off >= 1; off >>= 1) v += __shfl_xor(v, off);
        if (lane == 0) out[0] = (float)(v / (double)(B_ * N_));
    }
}

extern "C" void kernel_launch(void* const* d_in, const int* in_sizes, int n_in,
                              void* d_out, int out_size, void* d_ws, size_t ws_size,
                              hipStream_t stream) {
    const float* pred_boxes    = (const float*)d_in[0];
    const float* pred_logits   = (const float*)d_in[1];
    const float* target_boxes  = (const float*)d_in[2];
    const int*   target_labels = (const int*)d_in[3];
    float* out = (float*)d_out;

    char* ws = (char*)d_ws;
    double* partial = (double*)(ws);        // 64*8 = 512
    u32*    cnt     = (u32*)(ws + 512);     // 4

    hipMemsetAsync(cnt, 0, sizeof(u32), stream);  // capture-safe memset node
    hipLaunchKernelGGL(fused_kernel, dim3(B_), dim3(256), 0, stream,
                       pred_boxes, pred_logits, target_boxes, target_labels,
                       partial, cnt, out);
}

// Round 11
// 79.465 us; speedup vs baseline: 1.4435x; 1.4435x over previous
//
#include <hip/hip_runtime.h>
#include <math.h>

constexpr int B_ = 64, Q_ = 900, N_ = 100, C_ = 256;
constexpr float EPSF = 1e-6f;
constexpr float BOX_W = 5.0f, GIOU_W = 2.0f, CLS_W = 1.0f;
constexpr int KP = 15;   // preds per lane: 64*15 >= 900
constexpr int T_ = 10;   // targets per chunk
constexpr int CH_ = 10;  // chunks
constexpr int NW = 16;   // waves per block
typedef unsigned long long u64;
typedef unsigned int u32;

__device__ __forceinline__ float giou_f(float px0, float py0, float px1, float py1, float pa,
                                        float tx0, float ty0, float tx1, float ty1, float ta) {
    float ltx = fmaxf(px0, tx0), lty = fmaxf(py0, ty0);
    float rbx = fminf(px1, tx1), rby = fminf(py1, ty1);
    float w = fmaxf(rbx - ltx, 0.0f), h = fmaxf(rby - lty, 0.0f);
    float inter = w * h;
    float uni = pa + ta - inter;
    float iou = inter / (uni + EPSF);
    float ex0 = fminf(px0, tx0), ey0 = fminf(py0, ty0);
    float ex1 = fmaxf(px1, tx1), ey1 = fmaxf(py1, ty1);
    float ew = fmaxf(ex1 - ex0, 0.0f), eh = fmaxf(ey1 - ey0, 0.0f);
    float earea = ew * eh;
    return iou - (earea - uni) / (earea + EPSF);
}

// order-preserving float->uint (bijective): a>b as float <=> f2ord(a)>f2ord(b)
__device__ __forceinline__ u32 f2ord(float f) {
    u32 u = __float_as_uint(f);
    return (u & 0x80000000u) ? ~u : (u | 0x80000000u);
}

// canonical GCN wave64 max-reduce via DPP (rocPRIM pattern), result broadcast from lane 63
__device__ __forceinline__ u32 wave_max_u32(u32 x) {
    u32 t;
    t = (u32)__builtin_amdgcn_update_dpp((int)x, (int)x, 0x111, 0xf, 0xf, false); x = x > t ? x : t; // row_shr:1
    t = (u32)__builtin_amdgcn_update_dpp((int)x, (int)x, 0x112, 0xf, 0xf, false); x = x > t ? x : t; // row_shr:2
    t = (u32)__builtin_amdgcn_update_dpp((int)x, (int)x, 0x114, 0xf, 0xe, false); x = x > t ? x : t; // row_shr:4
    t = (u32)__builtin_amdgcn_update_dpp((int)x, (int)x, 0x118, 0xf, 0xc, false); x = x > t ? x : t; // row_shr:8
    t = (u32)__builtin_amdgcn_update_dpp((int)x, (int)x, 0x142, 0xa, 0xf, false); x = x > t ? x : t; // row_bcast:15
    t = (u32)__builtin_amdgcn_update_dpp((int)x, (int)x, 0x143, 0xc, 0xf, false); x = x > t ? x : t; // row_bcast:31
    return (u32)__builtin_amdgcn_readlane((int)x, 63);
}

// compute one target's exact-u32 column into LDS planes [KP][64] (lane stride 4B: conflict-free)
__device__ __forceinline__ void compute_col(
    u32 (*smat)[64], int nl, int n, int lane,
    const float* px0, const float* py0, const float* px1, const float* py1, const float* pa,
    const float* tx0s, const float* ty0s, const float* tx1s, const float* ty1s, const float* tas)
{
    float tx0 = tx0s[n], ty0 = ty0s[n], tx1 = tx1s[n], ty1 = ty1s[n], ta = tas[n];
    #pragma unroll
    for (int k = 0; k < KP; ++k) {
        int q = lane + (k << 6);
        u32 val = 0u;
        if (q < Q_) {
            float g = giou_f(px0[k], py0[k], px1[k], py1[k], pa[k], tx0, ty0, tx1, ty1, ta);
            val = f2ord(g);
        }
        smat[nl * KP + k][lane] = val;
    }
}

__global__ __launch_bounds__(1024, 1) void fused_kernel(
    const float* __restrict__ pred_boxes,    // [B,Q,4] cxcywh
    const float* __restrict__ pred_logits,   // [B,Q,C]
    const float* __restrict__ target_boxes,  // [B,N,4] xyxy
    const int*   __restrict__ target_labels, // [B,N]
    double* __restrict__ partial,            // [B]
    u32* __restrict__ cnt,                   // zeroed by async memset each launch
    float* __restrict__ out)
{
    const int b = blockIdx.x;
    const int tid = threadIdx.x;
    const int lane = tid & 63;
    const int wid = tid >> 6;

    __shared__ u32 s_mat[2][T_ * KP][64];    // 76.8 KB exact-ord planes, double-buffered
    __shared__ float tx0s[N_], ty0s[N_], tx1s[N_], ty1s[N_], tas[N_];
    __shared__ int labs[N_], s_ms[N_];
    __shared__ double s_wred[NW];
    __shared__ int s_last;

    // ---- P0: targets + labels ----
    if (tid < N_) {
        const float4 t4 = ((const float4*)(target_boxes + (size_t)b * N_ * 4))[tid];
        tx0s[tid] = t4.x; ty0s[tid] = t4.y; tx1s[tid] = t4.z; ty1s[tid] = t4.w;
        tas[tid] = (t4.z - t4.x) * (t4.w - t4.y);
        labs[tid] = target_labels[b * N_ + tid];
    }
    // per-lane pred boxes: only staging waves (1..10) need them
    float px0[KP], py0[KP], px1[KP], py1[KP], pa[KP];
    const float4* pbv = (const float4*)(pred_boxes + (size_t)b * Q_ * 4);
    if (wid >= 1 && wid <= 10) {
        #pragma unroll
        for (int k = 0; k < KP; ++k) {
            int q = lane + (k << 6);
            px0[k] = py0[k] = px1[k] = py1[k] = pa[k] = 0.0f;
            if (q < Q_) {
                float4 c = pbv[q];
                px0[k] = c.x - 0.5f * c.z; py0[k] = c.y - 0.5f * c.w;
                px1[k] = c.x + 0.5f * c.z; py1[k] = c.y + 0.5f * c.w;
                pa[k] = (px1[k] - px0[k]) * (py1[k] - py0[k]);
            }
        }
    }
    __syncthreads();

    // ---- prologue: staging waves compute chunk 0 (one column each) ----
    if (wid >= 1 && wid <= T_)
        compute_col(s_mat[0], wid - 1, wid - 1, lane, px0, py0, px1, py1, pa,
                    tx0s, ty0s, tx1s, ty1s, tas);
    __syncthreads();

    double acc = 0.0;
    u32 um = 0u;  // used bits among this lane's KP preds (resolve wave only)
    const float* lgbase = pred_logits + (size_t)b * Q_ * C_;

    // ---- pipelined main loop: w0 resolves c | w1-10 stage c+1 | w11-15 BCE c-1 ----
    for (int c = 0; c < CH_; ++c) {
        if (wid == 0) {
            const u32 (*smat)[64] = s_mat[c & 1];
            u32 wcur[KP];
            #pragma unroll
            for (int k = 0; k < KP; ++k) wcur[k] = smat[k][lane];
            #pragma unroll 1
            for (int nl = 0; nl < T_; ++nl) {
                const int n = c * T_ + nl;
                u32 wnext[KP];
                #pragma unroll
                for (int k = 0; k < KP; ++k)
                    wnext[k] = (nl + 1 < T_) ? smat[(nl + 1) * KP + k][lane] : 0u;
                // masked in-lane argmax (first occurrence wins => min k => min q on in-lane ties)
                u32 t1 = 0u; int k1 = 0;
                #pragma unroll
                for (int k = 0; k < KP; ++k) {
                    u32 v = ((um >> k) & 1u) ? 0u : wcur[k];
                    bool gt = v > t1;
                    k1 = gt ? k : k1;
                    t1 = gt ? v : t1;
                }
                u32 wval = wave_max_u32(t1);
                u64 bal = __ballot(t1 == wval);
                int lt = (int)__builtin_ctzll(bal);
                int wq = lt + (__builtin_amdgcn_readlane(k1, lt) << 6);
                if (__popcll(bal) > 1) {  // exact f32 ties only: pick min q
                    u64 mm = bal & (bal - 1);
                    while (mm) {
                        int l2 = (int)__builtin_ctzll(mm);
                        int qq = l2 + (__builtin_amdgcn_readlane(k1, l2) << 6);
                        wq = qq < wq ? qq : wq;
                        mm &= mm - 1;
                    }
                }
                if (lane == (wq & 63)) um |= 1u << (wq >> 6);
                if (lane == 0) s_ms[n] = wq;
                #pragma unroll
                for (int k = 0; k < KP; ++k) wcur[k] = wnext[k];
            }
        } else if (wid <= 10) {
            if (c + 1 < CH_)
                compute_col(s_mat[(c + 1) & 1], wid - 1, (c + 1) * T_ + (wid - 1), lane,
                            px0, py0, px1, py1, pa, tx0s, ty0s, tx1s, ty1s, tas);
        } else {
            if (c >= 1) {
                // BCE for chunk c-1: 2 rows per wave (s_ms visible since last barrier)
                #pragma unroll
                for (int r = 0; r < 2; ++r) {
                    const int n = (c - 1) * T_ + (wid - 11) + r * 5;
                    int q = s_ms[n];
                    int lab = labs[n];
                    const float4 xv = *(const float4*)(lgbase + (size_t)q * C_ + lane * 4);
                    float xs[4] = {xv.x, xv.y, xv.z, xv.w};
                    int base = lane * 4;
                    #pragma unroll
                    for (int j = 0; j < 4; ++j) {
                        float x = xs[j];
                        float tt = (base + j == lab) ? 1.0f : 0.0f;
                        acc += (double)(fmaxf(x, 0.0f) - x * tt + log1pf(expf(-fabsf(x))));
                    }
                }
            }
        }
        __syncthreads();
    }

    // ---- tail BCE: last chunk rows 90..99, waves 6..15 one row each ----
    if (wid >= 6) {
        const int n = (CH_ - 1) * T_ + (wid - 6);
        int q = s_ms[n];
        int lab = labs[n];
        const float4 xv = *(const float4*)(lgbase + (size_t)q * C_ + lane * 4);
        float xs[4] = {xv.x, xv.y, xv.z, xv.w};
        int base = lane * 4;
        #pragma unroll
        for (int j = 0; j < 4; ++j) {
            float x = xs[j];
            float tt = (base + j == lab) ? 1.0f : 0.0f;
            acc += (double)(fmaxf(x, 0.0f) - x * tt + log1pf(expf(-fabsf(x))));
        }
    }
    acc *= (double)CLS_W;

    // ---- box losses: one target per thread (tid < 100) ----
    if (tid < N_) {
        int q = s_ms[tid];
        float4 c = pbv[q];
        float tx0 = tx0s[tid], ty0 = ty0s[tid], tx1 = tx1s[tid], ty1 = ty1s[tid];
        float tcx = (tx0 + tx1) * 0.5f, tcy = (ty0 + ty1) * 0.5f;
        float tw = tx1 - tx0, th = ty1 - ty0;
        float l1 = fabsf(c.x - tcx) + fabsf(c.y - tcy) + fabsf(c.z - tw) + fabsf(c.w - th);
        float x0 = c.x - 0.5f * c.z, y0 = c.y - 0.5f * c.w;
        float x1 = c.x + 0.5f * c.z, y1 = c.y + 0.5f * c.w;
        float pa2 = (x1 - x0) * (y1 - y0);
        float g = giou_f(x0, y0, x1, y1, pa2, tx0, ty0, tx1, ty1, tas[tid]);
        acc += (double)(BOX_W * l1) + (double)(GIOU_W * (1.0f - g));
    }

    // ---- reduce: per-wave f64 butterfly -> 16 partials -> serial fixed-order sum ----
    #pragma unroll
    for (int off = 32; off >= 1; off >>= 1) acc += __shfl_xor(acc, off);
    if (lane == 0) s_wred[wid] = acc;
    __syncthreads();

    if (tid == 0) {
        double s = 0.0;
        #pragma unroll
        for (int w = 0; w < NW; ++w) s += s_wred[w];
        __hip_atomic_store(&partial[b], s, __ATOMIC_RELEASE, __HIP_MEMORY_SCOPE_AGENT);
        u32 old = __hip_atomic_fetch_add(cnt, 1u, __ATOMIC_ACQ_REL, __HIP_MEMORY_SCOPE_AGENT);
        s_last = (old == (u32)(B_ - 1)) ? 1 : 0;
    }
    __syncthreads();
    if (s_last && tid < 64) {
        double v = __hip_atomic_load(&partial[lane], __ATOMIC_ACQUIRE, __HIP_MEMORY_SCOPE_AGENT);
        #pragma unroll
        for (int off = 32; off >= 1; off >>= 1) v += __shfl_xor(v, off);
        if (lane == 0) out[0] = (float)(v / (double)(B_ * N_));
    }
}

extern "C" void kernel_launch(void* const* d_in, const int* in_sizes, int n_in,
                              void* d_out, int out_size, void* d_ws, size_t ws_size,
                              hipStream_t stream) {
    const float* pred_boxes    = (const float*)d_in[0];
    const float* pred_logits   = (const float*)d_in[1];
    const float* target_boxes  = (const float*)d_in[2];
    const int*   target_labels = (const int*)d_in[3];
    float* out = (float*)d_out;

    char* ws = (char*)d_ws;
    double* partial = (double*)(ws);        // 64*8 = 512
    u32*    cnt     = (u32*)(ws + 512);     // 4

    hipMemsetAsync(cnt, 0, sizeof(u32), stream);  // capture-safe memset node
    hipLaunchKernelGGL(fused_kernel, dim3(B_), dim3(1024), 0, stream,
                       pred_boxes, pred_logits, target_boxes, target_labels,
                       partial, cnt, out);
}